// Round 1
// baseline (396.568 us; speedup 1.0000x reference)
//
#include <hip/hip_runtime.h>

#define NTOK 32
#define PADT 1
#define MLEN 512
#define NLEN 1024
#define INF_F 1000000000.0f
#define EPS_F 1e-7f
#define VSTRIDE 516  // >513, multiple of 4

// Dynamic LDS layout (floats):
//   nl[32][1024]            : -log(clip(p)) transposed [token][frame]
//   vb[3][VSTRIDE]          : rotating DP anti-diagonals
//   tok[512] (int)          : left-shifted tokens
//   wtot[8]  (int)          : per-wave nonpad counts

__global__ __launch_bounds__(512, 1) void align_loss_kernel(
    const int* __restrict__ y_true, const float* __restrict__ y_pred,
    float* __restrict__ partial)
{
  extern __shared__ float smem[];
  float* nl  = smem;                       // 32*1024
  float* vb  = smem + NTOK * NLEN;         // 3*VSTRIDE
  int*   tok = (int*)(vb + 3 * VSTRIDE);   // 512
  int*   wtot = tok + MLEN;                // 8

  const int b = blockIdx.x;
  const int t = threadIdx.x;
  const int lane = t & 63;
  const int wv = t >> 6;

  // ---- Phase A: left-shift compaction + seq_len (ballot prefix) ----
  int yt = y_true[b * MLEN + t];
  bool flag = (yt != PADT);
  unsigned long long m = __ballot(flag);
  int wprefix = __popcll(m & ((1ull << lane) - 1ull));
  if (lane == 0) wtot[wv] = __popcll(m);
  __syncthreads();
  int offs = 0, total = 0;
#pragma unroll
  for (int w = 0; w < 8; ++w) { int c = wtot[w]; if (w < wv) offs += c; total += c; }
  if (flag) tok[offs + wprefix] = yt;
  const int L = total;
  __syncthreads();
  const int mytok = (t < L) ? tok[t] : 0;     // token for cell row i = t+1
  const float* nlrow = nl + mytok * NLEN;
  const float* nl1 = nl + PADT * NLEN;        // insertion cost row

  // ---- Phase B: nl[tk][r] = -log(clip(y_pred[b,r,tk]/sum)) ----
  for (int r = t; r < NLEN; r += 512) {
    const float4* rp = (const float4*)(y_pred + ((size_t)b * NLEN + r) * NTOK);
    float4 q[8];
    float s = 0.f;
#pragma unroll
    for (int u = 0; u < 8; ++u) { q[u] = rp[u]; s += q[u].x + q[u].y + q[u].z + q[u].w; }
    float inv = 1.0f / s;
#pragma unroll
    for (int u = 0; u < 8; ++u) {
      float pv[4] = {q[u].x, q[u].y, q[u].z, q[u].w};
#pragma unroll
      for (int c = 0; c < 4; ++c) {
        float p = pv[c] * inv;
        p = fminf(fmaxf(p, EPS_F), 1.0f - EPS_F);
        nl[(u * 4 + c) * NLEN + r] = -__logf(p);
      }
    }
  }

  // ---- Phase C: init DP diagonals ----
  for (int idx = t; idx < 3 * VSTRIDE; idx += 512) vb[idx] = INF_F;
  __syncthreads();
  if (t == 0) {
    vb[0 * VSTRIDE + 0] = 0.0f;      // D[0][0]   (k=0 buffer)
    vb[1 * VSTRIDE + 0] = nl1[0];    // D[0][1] = ins[0]
    vb[1 * VSTRIDE + 1] = 1.0f;      // D[1][0] = DEL
  }
  __syncthreads();

  // ---- Phase D: wavefront DP, k = 2 .. L+N ----
  const int kend = L + NLEN;
  for (int k = 2; k <= kend; ++k) {
    float* vc = vb + (k % 3) * VSTRIDE;
    const float* p1 = vb + ((k + 2) % 3) * VSTRIDE;  // diag k-1
    const float* p2 = vb + ((k + 1) % 3) * VSTRIDE;  // diag k-2
    if (t == 0 && k <= NLEN) vc[0] = p1[0] + nl1[k - 1];  // D[0][k]
    const int i = t + 1;
    const int j = k - i;
    if (i <= L && j >= 0 && j <= NLEN) {
      float val = p1[i - 1] + 1.0f;                  // delete
      if (j >= 1) {
        float vm = p2[i - 1] + nlrow[j - 1];         // match/sub
        float vi = p1[i]     + nl1[j - 1];           // insert
        val = fminf(val, fminf(vm, vi));
      }
      vc[i] = val;
    }
    __syncthreads();
  }

  if (t == 0) partial[b] = vb[(kend % 3) * VSTRIDE + L];
}

__global__ void reduce_kernel(const float* __restrict__ partial, float* __restrict__ out) {
  if (threadIdx.x == 0) {
    float s = 0.f;
    for (int b = 0; b < 32; ++b) s += partial[b];
    out[0] = s;
  }
}

extern "C" void kernel_launch(void* const* d_in, const int* in_sizes, int n_in,
                              void* d_out, int out_size, void* d_ws, size_t ws_size,
                              hipStream_t stream) {
  const int*   y_true = (const int*)d_in[0];
  const float* y_pred = (const float*)d_in[1];
  float* out = (float*)d_out;
  float* partial = (float*)d_ws;

  const size_t lds_bytes = (size_t)(NTOK * NLEN + 3 * VSTRIDE) * sizeof(float)
                         + (size_t)(MLEN + 8) * sizeof(int);
  hipFuncSetAttribute((const void*)align_loss_kernel,
                      hipFuncAttributeMaxDynamicSharedMemorySize, (int)lds_bytes);

  hipLaunchKernelGGL(align_loss_kernel, dim3(32), dim3(512), lds_bytes, stream,
                     y_true, y_pred, partial);
  hipLaunchKernelGGL(reduce_kernel, dim3(1), dim3(64), 0, stream, partial, out);
}

// Round 2
// 95.568 us; speedup vs baseline: 4.1496x; 4.1496x over previous
//
#include <hip/hip_runtime.h>

#define NTOK 32
#define PADT 1
#define MLEN 512
#define NLEN 1024
#define EPS_F 1e-7f
#define CCH  128          // columns per chunk
#define NC   8            // NLEN / CCH
#define NWAVE 4
#define BSTRIDE 256       // boundary buffer stride (floats), padded for prefetch overrun
#define NL_PAD 128

// LDS layout (floats):
//   P0s[1280]              : P0s[m] = D[0][m+1] (row-0 prefix sums), padded
//   bnd[5][2][BSTRIDE]     : cross-wave boundary rows, double buffered
//   tok[512] (int)         : left-shifted tokens
//   wtmp[16]               : scan/compaction temps
//   nl[32*1024 + NL_PAD]   : -log(clip(p)) transposed [token][frame], pad for overrun

template <bool MASKED>
__device__ __forceinline__ void do_iter(
    const float*& q0c, const float*& q1c, const float*& qic, const float*& qbc,
    float (&C0)[8], float (&C1)[8], float (&CI)[8], float (&CB)[8],
    float (&N0)[8], float (&N1)[8], float (&NI)[8], float (&NB)[8],
    float& dcur0, float& dcur1, float& diag0,
    int& sb, const int lane, float* __restrict__ bw)
{
  float wreg[8];
  // prefetch next 8 steps of all 4 streams
#pragma unroll
  for (int k = 0; k < 8; ++k) {
    N0[k] = q0c[8 + k]; N1[k] = q1c[8 + k];
    NI[k] = qic[8 + k]; NB[k] = qbc[8 + k];
  }
#pragma unroll
  for (int k = 0; k < 8; ++k) {
    // up0 = lane>0 ? dcur1[lane-1] : boundary value  (wave_shr:1, old = bv)
    float up0 = __int_as_float(__builtin_amdgcn_update_dpp(
        __float_as_int(CB[k]), __float_as_int(dcur1), 0x138, 0xF, 0xF, false));
    float a0 = diag0 + C0[k];      // substitute
    float b0 = up0 + 1.0f;         // delete
    float c0 = dcur0 + CI[k];      // insert
    float m0 = fminf(fminf(a0, b0), c0);
    float a1 = dcur0 + C1[k];      // diag for row r1 = old dcur0
    float b1 = m0 + 1.0f;          // up for row r1 = new dcur0
    float c1 = dcur1 + CI[k];
    float m1 = fminf(fminf(a1, b1), c1);
    if (MASKED) {
      int rsk = sb + k - lane;
      bool upd = rsk < CCH;
      bool act = ((unsigned)rsk) < (unsigned)CCH;
      diag0 = upd ? up0 : diag0;
      dcur0 = act ? m0 : dcur0;
      dcur1 = act ? m1 : dcur1;
    } else {
      diag0 = up0; dcur0 = m0; dcur1 = m1;
    }
    wreg[k] = m1;
  }
  // lane 63 exports its bottom row for the next wave
  if (lane == 63) {
    int slot0 = sb - 63;
#pragma unroll
    for (int k = 0; k < 8; ++k) {
      int sl = slot0 + k;
      if (MASKED) sl = (sl < 0) ? 0 : sl;   // garbage pre-writes land on slot 0, overwritten later
      bw[sl] = wreg[k];
    }
  }
  q0c += 8; q1c += 8; qic += 8; qbc += 8; sb += 8;
}

__global__ __launch_bounds__(256, 1) void align_loss_kernel(
    const int* __restrict__ y_true, const float* __restrict__ y_pred,
    float* __restrict__ partial)
{
  extern __shared__ float smem[];
  float* P0s  = smem;                         // 1280
  float* bnd  = P0s + 1280;                   // 5*2*BSTRIDE = 2560
  int*   tok  = (int*)(bnd + 5 * 2 * BSTRIDE);// 512 ints
  float* wtmp = (float*)(tok + MLEN);         // 16
  int*   wti  = (int*)wtmp;
  float* nl   = wtmp + 16;                    // 32*1024 + NL_PAD

  const int b = blockIdx.x;
  const int t = threadIdx.x;
  const int lane = t & 63;
  const int wv = t >> 6;

  // ---- Phase A: left-shift compaction (2 halves of 256) ----
  tok[t] = 0; tok[t + 256] = 0;
  __syncthreads();
  int total = 0;
  for (int h = 0; h < 2; ++h) {
    int yt = y_true[b * MLEN + h * 256 + t];
    bool f = (yt != PADT);
    unsigned long long m = __ballot(f);
    int wp = __popcll(m & ((1ull << lane) - 1ull));
    if (lane == 0) wti[8 + wv] = __popcll(m);
    __syncthreads();
    int offs = total, ht = 0;
#pragma unroll
    for (int w2 = 0; w2 < NWAVE; ++w2) { int cnt = wti[8 + w2]; if (w2 < wv) offs += cnt; ht += cnt; }
    if (f) tok[offs + wp] = yt;
    total += ht;
    __syncthreads();
  }
  const int L = total;

  // ---- Phase B: nl[tk][r] = -log(clip(y_pred[b,r,tk]/sum)) ----
  for (int r = t; r < NLEN; r += 256) {
    const float4* rp = (const float4*)(y_pred + ((size_t)b * NLEN + r) * NTOK);
    float4 q[8]; float s = 0.f;
#pragma unroll
    for (int u = 0; u < 8; ++u) { q[u] = rp[u]; s += q[u].x + q[u].y + q[u].z + q[u].w; }
    float inv = 1.0f / s;
#pragma unroll
    for (int u = 0; u < 8; ++u) {
      float pv[4] = {q[u].x, q[u].y, q[u].z, q[u].w};
#pragma unroll
      for (int c2 = 0; c2 < 4; ++c2) {
        float p = pv[c2] * inv;
        p = fminf(fmaxf(p, EPS_F), 1.0f - EPS_F);
        nl[(u * 4 + c2) * NLEN + r] = -__logf(p);
      }
    }
  }
  __syncthreads();

  // ---- Row-0 prefix scan: P0s[m] = D[0][m+1] = sum_{r<=m} ins[r] ----
  {
    float4 iv = *(const float4*)(nl + PADT * NLEN + 4 * t);
    float p1 = iv.x, p2 = iv.x + iv.y, p3 = p2 + iv.z, s4 = p3 + iv.w;
    float x = s4;
#pragma unroll
    for (int d = 1; d < 64; d <<= 1) {
      float y = __shfl_up(x, d);
      if (lane >= d) x += y;
    }
    if (lane == 63) wtmp[wv] = x;
    __syncthreads();
    float pre = x - s4;
#pragma unroll
    for (int w2 = 0; w2 < NWAVE; ++w2) if (w2 < wv) pre += wtmp[w2];
    *(float4*)(P0s + 4 * t) = make_float4(pre + p1, pre + p2, pre + p3, pre + s4);
  }

  // ---- DP state: lane owns rows r0 = 2t+1, r1 = 2t+2 ----
  const int r0 = 2 * t + 1;
  const int tk0 = tok[2 * t];
  const int tk1 = tok[2 * t + 1];
  const float* sub0 = nl + tk0 * NLEN;
  const float* sub1 = nl + tk1 * NLEN;
  const float* insp = nl + PADT * NLEN;
  float dcur0 = (float)r0;        // D[r0][0]
  float dcur1 = (float)(r0 + 1);  // D[r1][0]
  float diag0 = (float)(r0 - 1);  // D[r0-1][0]

  // ---- Systolic chunk phases ----
  for (int p = 0; p < NC + NWAVE - 1; ++p) {
    __syncthreads();
    const int c = p - wv;
    if (c < 0 || c >= NC) continue;
    const int base = c * CCH;
    const float* q0c = sub0 + base - lane;
    const float* q1c = sub1 + base - lane;
    const float* qic = insp + base - lane;
    const float* qbc = (wv == 0) ? (P0s + base)
                                 : (bnd + (wv * 2 + (p & 1)) * BSTRIDE);
    float* bw = bnd + ((wv + 1) * 2 + ((p + 1) & 1)) * BSTRIDE;

    float A0[8], A1[8], AI[8], AB[8], B0[8], B1[8], BI[8], BB[8];
#pragma unroll
    for (int k = 0; k < 8; ++k) { A0[k] = q0c[k]; A1[k] = q1c[k]; AI[k] = qic[k]; AB[k] = qbc[k]; }
    int sb = 0;
    // ramp-in (masked): iters 0..7
    for (int it2 = 0; it2 < 4; ++it2) {
      do_iter<true>(q0c, q1c, qic, qbc, A0, A1, AI, AB, B0, B1, BI, BB, dcur0, dcur1, diag0, sb, lane, bw);
      do_iter<true>(q0c, q1c, qic, qbc, B0, B1, BI, BB, A0, A1, AI, AB, dcur0, dcur1, diag0, sb, lane, bw);
    }
    // middle (all lanes active): iters 8..15
    for (int it2 = 0; it2 < 4; ++it2) {
      do_iter<false>(q0c, q1c, qic, qbc, A0, A1, AI, AB, B0, B1, BI, BB, dcur0, dcur1, diag0, sb, lane, bw);
      do_iter<false>(q0c, q1c, qic, qbc, B0, B1, BI, BB, A0, A1, AI, AB, dcur0, dcur1, diag0, sb, lane, bw);
    }
    // ramp-out (masked): iters 16..23
    for (int it2 = 0; it2 < 4; ++it2) {
      do_iter<true>(q0c, q1c, qic, qbc, A0, A1, AI, AB, B0, B1, BI, BB, dcur0, dcur1, diag0, sb, lane, bw);
      do_iter<true>(q0c, q1c, qic, qbc, B0, B1, BI, BB, A0, A1, AI, AB, dcur0, dcur1, diag0, sb, lane, bw);
    }
  }

  // ---- Extract D[L][N] ----
  if (r0 == L) partial[b] = dcur0;
  if (r0 + 1 == L) partial[b] = dcur1;
  if (L == 0 && t == 0) partial[b] = P0s[NLEN - 1];
}

__global__ void reduce_kernel(const float* __restrict__ partial, float* __restrict__ out) {
  if (threadIdx.x == 0) {
    float s = 0.f;
    for (int b2 = 0; b2 < 32; ++b2) s += partial[b2];
    out[0] = s;
  }
}

extern "C" void kernel_launch(void* const* d_in, const int* in_sizes, int n_in,
                              void* d_out, int out_size, void* d_ws, size_t ws_size,
                              hipStream_t stream) {
  const int*   y_true = (const int*)d_in[0];
  const float* y_pred = (const float*)d_in[1];
  float* out = (float*)d_out;
  float* partial = (float*)d_ws;

  const size_t lds_words = 1280 + 5 * 2 * BSTRIDE + MLEN /*tok ints*/ + 16
                         + (size_t)NTOK * NLEN + NL_PAD;
  const size_t lds_bytes = lds_words * sizeof(float);

  hipFuncSetAttribute((const void*)align_loss_kernel,
                      hipFuncAttributeMaxDynamicSharedMemorySize, (int)lds_bytes);

  hipLaunchKernelGGL(align_loss_kernel, dim3(32), dim3(256), lds_bytes, stream,
                     y_true, y_pred, partial);
  hipLaunchKernelGGL(reduce_kernel, dim3(1), dim3(64), 0, stream, partial, out);
}